// Round 12
// baseline (397.363 us; speedup 1.0000x reference)
//
#include <hip/hip_runtime.h>
#include <hip/hip_bf16.h>
#include <math.h>

#define LMAX 360
#define MMAX 361
#define NLAT 361
#define NLON 720
#define BC   32
#define MT   (BC*2*NLAT)    // 23104 real rows
#define NLATP 364           // padded k-stride for 8-B-aligned interQ stores
#define MTP  (BC*2*NLATP)   // 23296 padded rows
#define QT   722            // valid K (2*MMAX) for stage-2 GEMM
#define KP   736            // stage-2 padded K = 23*32
#define NP   768            // stage-2 padded N
#define BM   128
#define BN   128
#define BK   32

typedef __attribute__((ext_vector_type(8))) short short8;
typedef __attribute__((ext_vector_type(4))) short short4v;
typedef __attribute__((ext_vector_type(4))) float f32x4;

static __device__ __forceinline__ short f2bf(float v) {
    __hip_bfloat16 h = __float2bfloat16(v);
    return *reinterpret_cast<short*>(&h);
}

// ---------------------------------------------------------------------------
// prep_x (unchanged, proven): x fp32 [bc][f][l][m][ri] -> xT bf16
// [m][src*32+bc][l], src = f*2 + ri, rows 360 bf16 = 720 B.
// ---------------------------------------------------------------------------
__global__ __launch_bounds__(256) void sht_prep_x(
    const float* __restrict__ x, __hip_bfloat16* __restrict__ xT)
{
    const int m0 = blockIdx.x * 32;
    const int l0 = blockIdx.y * 64;
    const int bc = blockIdx.z >> 1, f = blockIdx.z & 1;
    __shared__ float2 tile[64][33];
    const float2* __restrict__ x2 = (const float2*)x;
    const int t = threadIdx.x;
    const int rm = t & 31, rl = t >> 5;

    const int mm = min(m0 + rm, MMAX - 1);
    #pragma unroll
    for (int r = 0; r < 8; ++r) {
        int l = min(l0 + rl + r * 8, LMAX - 1);
        tile[rl + r * 8][rm] = x2[((size_t)(bc * 2 + f) * LMAX + l) * MMAX + mm];
    }
    __syncthreads();

    const int tm = t >> 3, lg = t & 7;
    const int m = m0 + tm;
    if (m >= MMAX) return;
    const int lw = l0 + lg * 8;
    if (lw >= LMAX) return;          // 360 is granule-aligned (45*8)

    short8 re, im;
    #pragma unroll
    for (int e = 0; e < 8; ++e) {
        float2 v = tile[lg * 8 + e][tm];
        re[e] = f2bf(v.x);
        im[e] = f2bf(v.y);
    }
    size_t mb = (size_t)m * (128 * LMAX);
    *(short8*)((short*)xT + mb + (size_t)((f * 2 + 0) * 32 + bc) * LMAX + lw) = re;
    *(short8*)((short*)xT + mb + (size_t)((f * 2 + 1) * 32 + bc) * LMAX + lw) = im;
}

// ---------------------------------------------------------------------------
// gemm1 v7 (merged p-halves): per-m MFMA GEMM, 6 l-chunks of 64.
//   acc[k][c] += A0[k][l]*(sgn*B[src(0,pl)]) + A1[k][l]*(sgn*B[src(1,pl)])
// Per chunk: stage A0 (d0) and A1 (d1) into two LDS tiles + ONE sign-free
// source-indexed B tile shared by both halves (xT traffic halved vs R11).
// srcT row-selection + sgnT XOR applied at B-fragment read (VALU, cheap).
// 48 in-flight dwords/thread at depth-1 == R11-depth-2 MLP, no extra VGPR.
// Stores: packed 8-B into padded interQ (proven R11).
// ---------------------------------------------------------------------------
__global__ __launch_bounds__(256, 3) void sht_gemm1(
    const float* __restrict__ dpct, const __hip_bfloat16* __restrict__ xT,
    __hip_bfloat16* __restrict__ interQ)
{
    const int m  = blockIdx.x;
    const int K0 = blockIdx.y * 96;

    __shared__ __align__(16) char Als0[96 * 128];    // d0 [k][64l bf16]
    __shared__ __align__(16) char Als1[96 * 128];    // d1 [k][64l bf16]
    __shared__ __align__(16) char BlsB[128 * 128];   // [src*32+bc][64l bf16]

    const int t    = threadIdx.x;
    const int lane = t & 63;
    const int wave = t >> 6;
    const int wm = (wave >> 1) * 48;   // 3 M-frags
    const int wn = (wave & 1) * 64;    // 4 N-frags
    const int fr = lane & 15;
    const int lq = lane >> 4;

    // A staging: 768 tasks (kd, lo) per half, 3 per thread (both halves share)
    int kdv[3], lov[3], kcl[3];
    #pragma unroll
    for (int it = 0; it < 3; ++it) {
        int task = it * 256 + t;
        kdv[it] = task % 96;
        lov[it] = task / 96;
        kcl[it] = min(K0 + kdv[it], 360);   // clamped k (garbage rows dropped)
    }
    // B staging: row cB = src*32+bc directly (source-indexed, sign-free)
    const int cB  = t >> 1;
    const int g0B = (t & 1) * 4;

    const int            srcT[8] = {0, 1, 2, 3, 3, 2, 1, 0};
    const unsigned short sgnT[8] = {0, 0, 0x8000, 0x8000, 0x8000, 0, 0x8000, 0};

    f32x4 acc[3][4];
    const f32x4 zero = {0.f, 0.f, 0.f, 0.f};
    #pragma unroll
    for (int i = 0; i < 3; ++i)
        #pragma unroll
        for (int j = 0; j < 4; ++j) acc[i][j] = zero;

    // prefetch registers (fixed names, no pointer indirection — R10 lesson)
    float  a0_[3][8], a1_[3][8];
    bool   av_[3];
    short8 bpf[4];
    bool   bvB[4];

#define LOAD_AB(ss) {                                                          \
    const int l0_ = (ss) * 64;                                                 \
    const short* bb_ = (const short*)xT + (size_t)m * (128 * LMAX) +           \
                       (size_t)cB * LMAX;                                      \
    _Pragma("unroll")                                                          \
    for (int i = 0; i < 4; ++i) {                                              \
        int lg2_ = l0_ + (g0B + i) * 8;                                        \
        bvB[i] = (lg2_ < LMAX);                                                \
        int lcl_ = bvB[i] ? lg2_ : 0;                                          \
        bpf[i] = *(const short8*)(bb_ + lcl_);                                 \
    }                                                                          \
    _Pragma("unroll")                                                          \
    for (int it = 0; it < 3; ++it) {                                           \
        int lb_ = l0_ + lov[it] * 8;                                           \
        av_[it] = (lb_ < LMAX);                                                \
        int lcl_ = av_[it] ? lb_ : 0;                                          \
        const float* s0_ = dpct + ((size_t)m * LMAX + lcl_) * NLAT + kcl[it];  \
        const float* s1_ = dpct + (((size_t)MMAX + m) * LMAX + lcl_) * NLAT    \
                           + kcl[it];                                          \
        _Pragma("unroll")                                                      \
        for (int e = 0; e < 8; ++e) {                                          \
            a0_[it][e] = s0_[(size_t)e * NLAT];                                \
            a1_[it][e] = s1_[(size_t)e * NLAT];                                \
        }                                                                      \
    } }

#define WRITE_AB() {                                                           \
    _Pragma("unroll")                                                          \
    for (int it = 0; it < 3; ++it) {                                           \
        short8 w0_, w1_;                                                       \
        _Pragma("unroll")                                                      \
        for (int e = 0; e < 8; ++e) {                                          \
            w0_[e] = av_[it] ? f2bf(a0_[it][e]) : (short)0;                    \
            w1_[e] = av_[it] ? f2bf(a1_[it][e]) : (short)0;                    \
        }                                                                      \
        int kd_ = kdv[it], lo_ = lov[it];                                      \
        int off_ = kd_ * 128 + ((lo_ ^ (kd_ & 7)) << 4);                       \
        *(short8*)(Als0 + off_) = w0_;                                         \
        *(short8*)(Als1 + off_) = w1_;                                         \
    }                                                                          \
    _Pragma("unroll")                                                          \
    for (int i = 0; i < 4; ++i) {                                              \
        short8 v_ = bpf[i];                                                    \
        _Pragma("unroll")                                                      \
        for (int e = 0; e < 8; ++e) v_[e] = bvB[i] ? v_[e] : (short)0;         \
        int g_ = g0B + i;                                                      \
        *(short8*)(BlsB + cB * 128 + ((g_ ^ (cB & 7)) << 4)) = v_;             \
    } }

    auto compute = [&]() {
        #pragma unroll
        for (int kk = 0; kk < 2; ++kk) {
            const int g = kk * 4 + lq;
            short8 af0[3], af1[3];
            #pragma unroll
            for (int mi = 0; mi < 3; ++mi) {
                int k = wm + mi * 16 + fr;
                int off = k * 128 + ((g ^ (k & 7)) << 4);
                af0[mi] = *(const short8*)(Als0 + off);
                af1[mi] = *(const short8*)(Als1 + off);
            }
            #pragma unroll
            for (int h = 0; h < 2; ++h) {
                #pragma unroll
                for (int ni = 0; ni < 4; ++ni) {
                    int pl = 2 * (wave & 1) + (ni >> 1);     // plane of this frag
                    int rB = srcT[h * 4 + pl] * 32 + (ni & 1) * 16 + fr;
                    short8 bg = *(const short8*)(
                        BlsB + rB * 128 + ((g ^ (rB & 7)) << 4));
                    short sg = (short)sgnT[h * 4 + pl];
                    #pragma unroll
                    for (int e = 0; e < 8; ++e) bg[e] ^= sg;
                    #pragma unroll
                    for (int mi = 0; mi < 3; ++mi)
                        acc[mi][ni] = __builtin_amdgcn_mfma_f32_16x16x32_bf16(
                            h ? af1[mi] : af0[mi], bg, acc[mi][ni], 0, 0, 0);
                }
            }
        }
    };

    LOAD_AB(0);

    #pragma unroll 1
    for (int s = 0; s < 6; ++s) {
        __syncthreads();          // previous step's LDS reads complete
        WRITE_AB();
        __syncthreads();
        if (s < 5) LOAD_AB(s + 1);
        compute();
    }

#undef LOAD_AB
#undef WRITE_AB

    // store (packed 8-B): k = K0 + wm + mi*16 + lq*4 + r ; c = wn + ni*16 + fr
    #pragma unroll
    for (int mi = 0; mi < 3; ++mi) {
        int kr = K0 + wm + mi * 16 + lq * 4;
        #pragma unroll
        for (int ni = 0; ni < 4; ++ni) {
            int c = wn + ni * 16 + fr;
            int pl = c >> 5, bc = c & 31;
            int ri = pl & 1, tt = pl >> 1;
            size_t qb = (size_t)(2 * m + ri) * MTP + (size_t)(bc * 2 + tt) * NLATP;
            if (kr + 3 <= 360) {
                short4v w;
                #pragma unroll
                for (int r = 0; r < 4; ++r) w[r] = f2bf(acc[mi][ni][r]);
                *(short4v*)((short*)interQ + qb + kr) = w;
            } else if (kr <= 360) {   // kr == 360 (4-aligned): single element
                ((short*)interQ)[qb + kr] = f2bf(acc[mi][ni][0]);
            }
        }
    }
}

// ---------------------------------------------------------------------------
// Transpose interQ [722][MTP padded] -> interT [23104 compact][736]
// Rm maps compact row R to padded row: Rm = (R/361)*364 + R%361.
// ---------------------------------------------------------------------------
__global__ __launch_bounds__(256) void sht_transpose(
    const __hip_bfloat16* __restrict__ inQ, __hip_bfloat16* __restrict__ outT)
{
    __shared__ __hip_bfloat16 tile[64][65];
    const int R0 = blockIdx.x * 64;
    const int q0 = blockIdx.y * 64;
    const int tx = threadIdx.x & 63;
    const int ty = threadIdx.x >> 6;
    const __hip_bfloat16 zv = __float2bfloat16(0.f);

    const int R  = R0 + tx;
    const int Rm = (R / NLAT) * NLATP + (R % NLAT);

    for (int qq = ty; qq < 64; qq += 4) {
        int q = q0 + qq;
        tile[qq][tx] = (q < QT) ? inQ[(size_t)q * MTP + Rm] : zv;
    }
    __syncthreads();
    if (q0 + tx < KP) {
        for (int rr = ty; rr < 64; rr += 4) {
            outT[(size_t)(R0 + rr) * KP + q0 + tx] = tile[tx][rr];
        }
    }
}

// ---------------------------------------------------------------------------
// W table [NP=768][KP=736] bf16
// ---------------------------------------------------------------------------
__global__ __launch_bounds__(256) void sht_make_w(__hip_bfloat16* __restrict__ W)
{
    const int idx = blockIdx.x * 256 + threadIdx.x;
    const int j = idx / KP;
    const int q = idx % KP;
    float v = 0.f;
    if (j < NLON && q < QT) {
        int m = q >> 1;
        float coef = (m == 0 || m == 360) ? 1.f : 2.f;
        int ph = (m * j) % 720;
        float ang = (float)ph * (float)(2.0 * M_PI / 720.0);
        float s, c;
        __sincosf(ang, &s, &c);
        v = (q & 1) ? (-coef * s) : (coef * c);
    }
    W[idx] = __float2bfloat16(v);
}

// ---------------------------------------------------------------------------
// Stage 2 GEMM (unchanged, proven): out[R][j] = sum_q interT[R][q] * W[j][q]
// ---------------------------------------------------------------------------
__global__ __launch_bounds__(256) void sht_gemm(
    const __hip_bfloat16* __restrict__ A,   // [MT][KP]
    const __hip_bfloat16* __restrict__ W,   // [NP][KP]
    float* __restrict__ out)                // [MT][NLON]
{
    __shared__ __align__(16) __hip_bfloat16 As[BM * BK];
    __shared__ __align__(16) __hip_bfloat16 Bs[BN * BK];
    const int t  = threadIdx.x;
    const int R0 = blockIdx.x * BM;
    const int J0 = blockIdx.y * BN;

    const int rowA = t >> 2;
    const int kc   = (t & 3) * 8;
    const int gr0  = min(R0 + rowA,      MT - 1);
    const int gr1  = min(R0 + rowA + 64, MT - 1);
    const __hip_bfloat16* pa0 = A + (size_t)gr0 * KP + kc;
    const __hip_bfloat16* pa1 = A + (size_t)gr1 * KP + kc;
    const __hip_bfloat16* pb0 = W + (size_t)(J0 + rowA) * KP + kc;
    const __hip_bfloat16* pb1 = W + (size_t)(J0 + rowA + 64) * KP + kc;

    const int lane = t & 63;
    const int wave = t >> 6;
    const int wm = (wave >> 1) * 64;
    const int wn = (wave & 1) * 64;
    const int fr = lane & 15;
    const int kg = (lane >> 4) * 8;

    f32x4 acc[4][4];
    const f32x4 zero = {0.f, 0.f, 0.f, 0.f};
    #pragma unroll
    for (int i = 0; i < 4; ++i)
        #pragma unroll
        for (int j = 0; j < 4; ++j) acc[i][j] = zero;

    short8 va0 = *(const short8*)pa0;
    short8 va1 = *(const short8*)pa1;
    short8 vb0 = *(const short8*)pb0;
    short8 vb1 = *(const short8*)pb1;

    for (int kt = 0; kt < KP / BK; ++kt) {
        __syncthreads();
        *(short8*)&As[t * 8]        = va0;
        *(short8*)&As[t * 8 + 2048] = va1;
        *(short8*)&Bs[t * 8]        = vb0;
        *(short8*)&Bs[t * 8 + 2048] = vb1;
        __syncthreads();

        if (kt + 1 < KP / BK) {
            const int ko = (kt + 1) * BK;
            va0 = *(const short8*)(pa0 + ko);
            va1 = *(const short8*)(pa1 + ko);
            vb0 = *(const short8*)(pb0 + ko);
            vb1 = *(const short8*)(pb1 + ko);
        }

        short8 af[4], bg[4];
        #pragma unroll
        for (int i = 0; i < 4; ++i)
            af[i] = *(const short8*)&As[(wm + i * 16 + fr) * BK + kg];
        #pragma unroll
        for (int i = 0; i < 4; ++i)
            bg[i] = *(const short8*)&Bs[(wn + i * 16 + fr) * BK + kg];

        #pragma unroll
        for (int mi = 0; mi < 4; ++mi)
            #pragma unroll
            for (int ni = 0; ni < 4; ++ni)
                acc[mi][ni] = __builtin_amdgcn_mfma_f32_16x16x32_bf16(
                    af[mi], bg[ni], acc[mi][ni], 0, 0, 0);
    }

    const int orow = (lane >> 4) * 4;
    #pragma unroll
    for (int mi = 0; mi < 4; ++mi) {
        #pragma unroll
        for (int ni = 0; ni < 4; ++ni) {
            #pragma unroll
            for (int r = 0; r < 4; ++r) {
                int row = R0 + wm + mi * 16 + orow + r;
                int col = J0 + wn + ni * 16 + fr;
                if (row < MT && col < NLON)
                    out[(size_t)row * NLON + col] = acc[mi][ni][r];
            }
        }
    }
}

// ---------------------------------------------------------------------------
// Workspace layout (R9 proved ws >= 280,297,728 B usable):
//   xT     [0,           33,269,760)
//   interT [34,009,088,  68,018,176)
//   interQ [70,254,592, 103,894,016)   padded [722][MTP] bf16
//   W      [104,857,600, 105,988,096)
// Liveness: xT:[prep->gemm1]  interQ:[gemm1->transpose]
//           interT:[transpose->gemm2]  W:[make_w->gemm2]
// ---------------------------------------------------------------------------
extern "C" void kernel_launch(void* const* d_in, const int* in_sizes, int n_in,
                              void* d_out, int out_size, void* d_ws, size_t ws_size,
                              hipStream_t stream)
{
    const float* x    = (const float*)d_in[0];
    const float* dpct = (const float*)d_in[1];
    float* out        = (float*)d_out;

    char* ws = (char*)d_ws;
    __hip_bfloat16* xT     = (__hip_bfloat16*)ws;
    __hip_bfloat16* interT = (__hip_bfloat16*)(ws + 34009088);
    __hip_bfloat16* interQ = (__hip_bfloat16*)(ws + 70254592);
    __hip_bfloat16* Wt     = (__hip_bfloat16*)(ws + 104857600);

    dim3 gp(12, 6, 64);
    sht_prep_x<<<gp, 256, 0, stream>>>(x, xT);

    dim3 g1(MMAX, 4);
    sht_gemm1<<<g1, 256, 0, stream>>>(dpct, xT, interQ);

    dim3 gt(MT / 64, 12);
    sht_transpose<<<gt, 256, 0, stream>>>(interQ, interT);

    sht_make_w<<<(NP * KP) / 256, 256, 0, stream>>>(Wt);

    dim3 gg((MT + BM - 1) / BM, NP / BN);
    sht_gemm<<<gg, 256, 0, stream>>>(interT, Wt, out);
}

// Round 13
// 312.783 us; speedup vs baseline: 1.2704x; 1.2704x over previous
//
#include <hip/hip_runtime.h>
#include <hip/hip_bf16.h>
#include <math.h>

#define LMAX 360
#define MMAX 361
#define NLAT 361
#define NLON 720
#define BC   32
#define MT   (BC*2*NLAT)    // 23104 real rows
#define NLATP 364           // padded k-stride for 8-B-aligned interQ stores
#define MTP  (BC*2*NLATP)   // 23296 padded rows
#define QT   722            // valid K (2*MMAX) for stage-2 GEMM
#define KP   736            // stage-2 padded K = 23*32
#define NP   768            // stage-2 padded N
#define BM   128
#define BN   128
#define BK   32

typedef __attribute__((ext_vector_type(8))) short short8;
typedef __attribute__((ext_vector_type(4))) short short4v;
typedef __attribute__((ext_vector_type(4))) float f32x4;

static __device__ __forceinline__ short f2bf(float v) {
    __hip_bfloat16 h = __float2bfloat16(v);
    return *reinterpret_cast<short*>(&h);
}

// ---------------------------------------------------------------------------
// prep_x (unchanged, proven): x fp32 [bc][f][l][m][ri] -> xT bf16
// [m][src*32+bc][l], src = f*2 + ri, rows 360 bf16 = 720 B.
// ---------------------------------------------------------------------------
__global__ __launch_bounds__(256) void sht_prep_x(
    const float* __restrict__ x, __hip_bfloat16* __restrict__ xT)
{
    const int m0 = blockIdx.x * 32;
    const int l0 = blockIdx.y * 64;
    const int bc = blockIdx.z >> 1, f = blockIdx.z & 1;
    __shared__ float2 tile[64][33];
    const float2* __restrict__ x2 = (const float2*)x;
    const int t = threadIdx.x;
    const int rm = t & 31, rl = t >> 5;

    const int mm = min(m0 + rm, MMAX - 1);
    #pragma unroll
    for (int r = 0; r < 8; ++r) {
        int l = min(l0 + rl + r * 8, LMAX - 1);
        tile[rl + r * 8][rm] = x2[((size_t)(bc * 2 + f) * LMAX + l) * MMAX + mm];
    }
    __syncthreads();

    const int tm = t >> 3, lg = t & 7;
    const int m = m0 + tm;
    if (m >= MMAX) return;
    const int lw = l0 + lg * 8;
    if (lw >= LMAX) return;          // 360 is granule-aligned (45*8)

    short8 re, im;
    #pragma unroll
    for (int e = 0; e < 8; ++e) {
        float2 v = tile[lg * 8 + e][tm];
        re[e] = f2bf(v.x);
        im[e] = f2bf(v.y);
    }
    size_t mb = (size_t)m * (128 * LMAX);
    *(short8*)((short*)xT + mb + (size_t)((f * 2 + 0) * 32 + bc) * LMAX + lw) = re;
    *(short8*)((short*)xT + mb + (size_t)((f * 2 + 1) * 32 + bc) * LMAX + lw) = im;
}

// ---------------------------------------------------------------------------
// gemm1 (R11 structure, byte-identical code; ONLY the grid mapping changed):
// grid is now (4, 361) — K0 in blockIdx.x (fast), m in blockIdx.y — so the
// 4 K-blocks sharing one m are DISPATCH-ADJACENT and co-resident: the xT
// panel is fetched from HBM once (L3 serves the redundant reads), dpct
// row-boundary lines are shared, and interQ row lines combine while hot.
//   D[k][combo] = sum_{l'} A[k][l'] * B[combo][l'], K = 768 (two 384 halves)
// A loads for step s+2 issue at step s (depth-2, proven 3.15 TB/s, no spill).
// ---------------------------------------------------------------------------
__global__ __launch_bounds__(256, 3) void sht_gemm1(
    const float* __restrict__ dpct, const __hip_bfloat16* __restrict__ xT,
    __hip_bfloat16* __restrict__ interQ)
{
    const int m  = blockIdx.y;          // <- swapped (was blockIdx.x)
    const int K0 = blockIdx.x * 96;     // <- swapped (was blockIdx.y)

    __shared__ __align__(16) char AlsB[96 * 128];    // [k][64l bf16], 128B rows
    __shared__ __align__(16) char BlsB[128 * 128];   // [c][64l bf16]

    const int t    = threadIdx.x;
    const int lane = t & 63;
    const int wave = t >> 6;
    const int wm = (wave >> 1) * 48;   // 3 M-frags
    const int wn = (wave & 1) * 64;    // 4 N-frags
    const int fr = lane & 15;
    const int lq = lane >> 4;

    // A staging: 768 tasks (kd, lo), 3 per thread
    int kdv[3], lov[3], kcl[3];
    #pragma unroll
    for (int it = 0; it < 3; ++it) {
        int task = it * 256 + t;
        kdv[it] = task % 96;
        lov[it] = task / 96;
        kcl[it] = min(K0 + kdv[it], 360);   // clamped k (garbage rows dropped)
    }
    // B staging: c = t>>1, granules g0B..g0B+3
    const int cB    = t >> 1;
    const int plane = cB >> 5, bcq = cB & 31;
    const int g0B   = (t & 1) * 4;

    const int            srcT[8] = {0, 1, 2, 3, 3, 2, 1, 0};
    const unsigned short sgnT[8] = {0, 0, 0x8000, 0x8000, 0x8000, 0, 0x8000, 0};

    f32x4 acc[3][4];
    const f32x4 zero = {0.f, 0.f, 0.f, 0.f};
    #pragma unroll
    for (int i = 0; i < 3; ++i)
        #pragma unroll
        for (int j = 0; j < 4; ++j) acc[i][j] = zero;

    // A prefetch: TWO hardcoded register sets (no pointer indirection!)
    float a0_[3][8], a1_[3][8];
    bool  v0_[3],    v1_[3];
    // B prefetch: single set
    short8 bpf[4];
    bool   bvB[4];
    short  bsgn = 0;

#define STEP_P(s)  ((s) >= 6 ? 1 : 0)
#define STEP_L(s)  (((s) % 6) * 64)

#define LOAD_A(AP, LV, ss) {                                                   \
    const int p_ = STEP_P(ss); const int l0_ = STEP_L(ss);                     \
    const size_t rowb_ = ((size_t)p_ * MMAX + m) * LMAX;                       \
    _Pragma("unroll")                                                          \
    for (int it = 0; it < 3; ++it) {                                           \
        int lb_ = l0_ + lov[it] * 8;                                           \
        LV[it] = (lb_ < LMAX);                                                 \
        int lcl_ = LV[it] ? lb_ : 0;                                           \
        const float* sp_ = dpct + (rowb_ + lcl_) * (size_t)NLAT + kcl[it];     \
        _Pragma("unroll")                                                      \
        for (int e = 0; e < 8; ++e)                                            \
            AP[it][e] = sp_[(size_t)e * NLAT];                                 \
    } }

#define LOAD_B(ss) {                                                           \
    const int p_ = STEP_P(ss); const int l0_ = STEP_L(ss);                     \
    int src_ = srcT[p_ * 4 + plane];                                           \
    bsgn = (short)sgnT[p_ * 4 + plane];                                        \
    const short* bb_ = (const short*)xT + (size_t)m * (128 * LMAX) +           \
                       (size_t)(src_ * 32 + bcq) * LMAX;                       \
    _Pragma("unroll")                                                          \
    for (int i = 0; i < 4; ++i) {                                              \
        int lg2_ = l0_ + (g0B + i) * 8;                                        \
        bvB[i] = (lg2_ < LMAX);                                                \
        int lcl_ = bvB[i] ? lg2_ : 0;                                          \
        bpf[i] = *(const short8*)(bb_ + lcl_);                                 \
    } }

#define WRITE_A(AP, LV) {                                                      \
    _Pragma("unroll")                                                          \
    for (int it = 0; it < 3; ++it) {                                           \
        short8 w_;                                                             \
        _Pragma("unroll")                                                      \
        for (int e = 0; e < 8; ++e)                                            \
            w_[e] = LV[it] ? f2bf(AP[it][e]) : (short)0;                       \
        int kd_ = kdv[it], lo_ = lov[it];                                      \
        *(short8*)(AlsB + kd_ * 128 + ((lo_ ^ (kd_ & 7)) << 4)) = w_;          \
    } }

#define WRITE_B() {                                                            \
    _Pragma("unroll")                                                          \
    for (int i = 0; i < 4; ++i) {                                              \
        short8 v_ = bpf[i];                                                    \
        _Pragma("unroll")                                                      \
        for (int e = 0; e < 8; ++e) {                                          \
            short xe_ = (short)(v_[e] ^ bsgn);                                 \
            v_[e] = bvB[i] ? xe_ : (short)0;                                   \
        }                                                                      \
        int g_ = g0B + i;                                                      \
        *(short8*)(BlsB + cB * 128 + ((g_ ^ (cB & 7)) << 4)) = v_;             \
    } }

    auto compute = [&]() {
        #pragma unroll
        for (int kk = 0; kk < 2; ++kk) {
            short8 af[3], bg[4];
            const int g = kk * 4 + lq;
            #pragma unroll
            for (int mi = 0; mi < 3; ++mi) {
                int k = wm + mi * 16 + fr;
                af[mi] = *(const short8*)(AlsB + k * 128 + ((g ^ (k & 7)) << 4));
            }
            #pragma unroll
            for (int ni = 0; ni < 4; ++ni) {
                int c = wn + ni * 16 + fr;
                bg[ni] = *(const short8*)(BlsB + c * 128 + ((g ^ (c & 7)) << 4));
            }
            #pragma unroll
            for (int mi = 0; mi < 3; ++mi)
                #pragma unroll
                for (int ni = 0; ni < 4; ++ni)
                    acc[mi][ni] = __builtin_amdgcn_mfma_f32_16x16x32_bf16(
                        af[mi], bg[ni], acc[mi][ni], 0, 0, 0);
        }
    };

    // prologue: B(0), A-set0(0), A-set1(1)
    LOAD_B(0);
    LOAD_A(a0_, v0_, 0);
    LOAD_A(a1_, v1_, 1);

    #pragma unroll 1
    for (int s = 0; s < 12; s += 2) {
        // ---- even step s: A-set0, B holds step s ----
        __syncthreads();
        WRITE_A(a0_, v0_);
        WRITE_B();
        __syncthreads();
        if (s + 1 < 12) LOAD_B(s + 1);          // B first (shallow)
        if (s + 2 < 12) LOAD_A(a0_, v0_, s + 2); // deep A prefetch
        compute();

        // ---- odd step s+1: A-set1, B holds step s+1 ----
        __syncthreads();
        WRITE_A(a1_, v1_);
        WRITE_B();
        __syncthreads();
        if (s + 2 < 12) LOAD_B(s + 2);
        if (s + 3 < 12) LOAD_A(a1_, v1_, s + 3);
        compute();
    }

#undef LOAD_A
#undef LOAD_B
#undef WRITE_A
#undef WRITE_B
#undef STEP_P
#undef STEP_L

    // store (packed 8-B): k = K0 + wm + mi*16 + lq*4 + r ; c = wn + ni*16 + fr
    // interQ padded rows (NLATP=364): qb+kr is a multiple of 4 -> 8-B aligned.
    #pragma unroll
    for (int mi = 0; mi < 3; ++mi) {
        int kr = K0 + wm + mi * 16 + lq * 4;
        #pragma unroll
        for (int ni = 0; ni < 4; ++ni) {
            int c = wn + ni * 16 + fr;
            int pl = c >> 5, bc = c & 31;
            int ri = pl & 1, tt = pl >> 1;
            size_t qb = (size_t)(2 * m + ri) * MTP + (size_t)(bc * 2 + tt) * NLATP;
            if (kr + 3 <= 360) {
                short4v w;
                #pragma unroll
                for (int r = 0; r < 4; ++r) w[r] = f2bf(acc[mi][ni][r]);
                *(short4v*)((short*)interQ + qb + kr) = w;
            } else if (kr <= 360) {   // kr == 360 (4-aligned): single element
                ((short*)interQ)[qb + kr] = f2bf(acc[mi][ni][0]);
            }
        }
    }
}

// ---------------------------------------------------------------------------
// Transpose interQ [722][MTP padded] -> interT [23104 compact][736]
// Rm maps compact row R to padded row: Rm = (R/361)*364 + R%361.
// ---------------------------------------------------------------------------
__global__ __launch_bounds__(256) void sht_transpose(
    const __hip_bfloat16* __restrict__ inQ, __hip_bfloat16* __restrict__ outT)
{
    __shared__ __hip_bfloat16 tile[64][65];
    const int R0 = blockIdx.x * 64;
    const int q0 = blockIdx.y * 64;
    const int tx = threadIdx.x & 63;
    const int ty = threadIdx.x >> 6;
    const __hip_bfloat16 zv = __float2bfloat16(0.f);

    const int R  = R0 + tx;
    const int Rm = (R / NLAT) * NLATP + (R % NLAT);

    for (int qq = ty; qq < 64; qq += 4) {
        int q = q0 + qq;
        tile[qq][tx] = (q < QT) ? inQ[(size_t)q * MTP + Rm] : zv;
    }
    __syncthreads();
    if (q0 + tx < KP) {
        for (int rr = ty; rr < 64; rr += 4) {
            outT[(size_t)(R0 + rr) * KP + q0 + tx] = tile[tx][rr];
        }
    }
}

// ---------------------------------------------------------------------------
// W table [NP=768][KP=736] bf16
// ---------------------------------------------------------------------------
__global__ __launch_bounds__(256) void sht_make_w(__hip_bfloat16* __restrict__ W)
{
    const int idx = blockIdx.x * 256 + threadIdx.x;
    const int j = idx / KP;
    const int q = idx % KP;
    float v = 0.f;
    if (j < NLON && q < QT) {
        int m = q >> 1;
        float coef = (m == 0 || m == 360) ? 1.f : 2.f;
        int ph = (m * j) % 720;
        float ang = (float)ph * (float)(2.0 * M_PI / 720.0);
        float s, c;
        __sincosf(ang, &s, &c);
        v = (q & 1) ? (-coef * s) : (coef * c);
    }
    W[idx] = __float2bfloat16(v);
}

// ---------------------------------------------------------------------------
// Stage 2 GEMM (unchanged, proven): out[R][j] = sum_q interT[R][q] * W[j][q]
// ---------------------------------------------------------------------------
__global__ __launch_bounds__(256) void sht_gemm(
    const __hip_bfloat16* __restrict__ A,   // [MT][KP]
    const __hip_bfloat16* __restrict__ W,   // [NP][KP]
    float* __restrict__ out)                // [MT][NLON]
{
    __shared__ __align__(16) __hip_bfloat16 As[BM * BK];
    __shared__ __align__(16) __hip_bfloat16 Bs[BN * BK];
    const int t  = threadIdx.x;
    const int R0 = blockIdx.x * BM;
    const int J0 = blockIdx.y * BN;

    const int rowA = t >> 2;
    const int kc   = (t & 3) * 8;
    const int gr0  = min(R0 + rowA,      MT - 1);
    const int gr1  = min(R0 + rowA + 64, MT - 1);
    const __hip_bfloat16* pa0 = A + (size_t)gr0 * KP + kc;
    const __hip_bfloat16* pa1 = A + (size_t)gr1 * KP + kc;
    const __hip_bfloat16* pb0 = W + (size_t)(J0 + rowA) * KP + kc;
    const __hip_bfloat16* pb1 = W + (size_t)(J0 + rowA + 64) * KP + kc;

    const int lane = t & 63;
    const int wave = t >> 6;
    const int wm = (wave >> 1) * 64;
    const int wn = (wave & 1) * 64;
    const int fr = lane & 15;
    const int kg = (lane >> 4) * 8;

    f32x4 acc[4][4];
    const f32x4 zero = {0.f, 0.f, 0.f, 0.f};
    #pragma unroll
    for (int i = 0; i < 4; ++i)
        #pragma unroll
        for (int j = 0; j < 4; ++j) acc[i][j] = zero;

    short8 va0 = *(const short8*)pa0;
    short8 va1 = *(const short8*)pa1;
    short8 vb0 = *(const short8*)pb0;
    short8 vb1 = *(const short8*)pb1;

    for (int kt = 0; kt < KP / BK; ++kt) {
        __syncthreads();
        *(short8*)&As[t * 8]        = va0;
        *(short8*)&As[t * 8 + 2048] = va1;
        *(short8*)&Bs[t * 8]        = vb0;
        *(short8*)&Bs[t * 8 + 2048] = vb1;
        __syncthreads();

        if (kt + 1 < KP / BK) {
            const int ko = (kt + 1) * BK;
            va0 = *(const short8*)(pa0 + ko);
            va1 = *(const short8*)(pa1 + ko);
            vb0 = *(const short8*)(pb0 + ko);
            vb1 = *(const short8*)(pb1 + ko);
        }

        short8 af[4], bg[4];
        #pragma unroll
        for (int i = 0; i < 4; ++i)
            af[i] = *(const short8*)&As[(wm + i * 16 + fr) * BK + kg];
        #pragma unroll
        for (int i = 0; i < 4; ++i)
            bg[i] = *(const short8*)&Bs[(wn + i * 16 + fr) * BK + kg];

        #pragma unroll
        for (int mi = 0; mi < 4; ++mi)
            #pragma unroll
            for (int ni = 0; ni < 4; ++ni)
                acc[mi][ni] = __builtin_amdgcn_mfma_f32_16x16x32_bf16(
                    af[mi], bg[ni], acc[mi][ni], 0, 0, 0);
    }

    const int orow = (lane >> 4) * 4;
    #pragma unroll
    for (int mi = 0; mi < 4; ++mi) {
        #pragma unroll
        for (int ni = 0; ni < 4; ++ni) {
            #pragma unroll
            for (int r = 0; r < 4; ++r) {
                int row = R0 + wm + mi * 16 + orow + r;
                int col = J0 + wn + ni * 16 + fr;
                if (row < MT && col < NLON)
                    out[(size_t)row * NLON + col] = acc[mi][ni][r];
            }
        }
    }
}

// ---------------------------------------------------------------------------
// Workspace layout (R9 proved ws >= 280,297,728 B usable):
//   xT     [0,           33,269,760)
//   interT [34,009,088,  68,018,176)
//   interQ [70,254,592, 103,894,016)   padded [722][MTP] bf16
//   W      [104,857,600, 105,988,096)
// Liveness: xT:[prep->gemm1]  interQ:[gemm1->transpose]
//           interT:[transpose->gemm2]  W:[make_w->gemm2]
// ---------------------------------------------------------------------------
extern "C" void kernel_launch(void* const* d_in, const int* in_sizes, int n_in,
                              void* d_out, int out_size, void* d_ws, size_t ws_size,
                              hipStream_t stream)
{
    const float* x    = (const float*)d_in[0];
    const float* dpct = (const float*)d_in[1];
    float* out        = (float*)d_out;

    char* ws = (char*)d_ws;
    __hip_bfloat16* xT     = (__hip_bfloat16*)ws;
    __hip_bfloat16* interT = (__hip_bfloat16*)(ws + 34009088);
    __hip_bfloat16* interQ = (__hip_bfloat16*)(ws + 70254592);
    __hip_bfloat16* Wt     = (__hip_bfloat16*)(ws + 104857600);

    dim3 gp(12, 6, 64);
    sht_prep_x<<<gp, 256, 0, stream>>>(x, xT);

    dim3 g1(4, MMAX);   // K0 fast: same-m blocks dispatch-adjacent (L3 reuse)
    sht_gemm1<<<g1, 256, 0, stream>>>(dpct, xT, interQ);

    dim3 gt(MT / 64, 12);
    sht_transpose<<<gt, 256, 0, stream>>>(interQ, interT);

    sht_make_w<<<(NP * KP) / 256, 256, 0, stream>>>(Wt);

    dim3 gg((MT + BM - 1) / BM, NP / BN);
    sht_gemm<<<gg, 256, 0, stream>>>(interT, Wt, out);
}